// Round 1
// baseline (1887.039 us; speedup 1.0000x reference)
//
#include <hip/hip_runtime.h>
#include <math.h>

#define L_SEQ 2048
#define DIM   2048
#define NH    16
#define HD    128
#define TDIM  6144   // 3*DIM

// ---------------------------------------------------------------------------
// GEMM:  C[M][N] = A[M][K] * B[N][K]^T  (+ optional bias[N])
// 128x128 tile, BK=16, 256 threads, 8x8 micro-tile.
// LDS k-major so the inner loop is ds_read_b128-fed (1 B/MAC).
// ---------------------------------------------------------------------------
template<bool BIAS>
__global__ __launch_bounds__(256)
void gemm_nt(const float* __restrict__ A, const float* __restrict__ B,
             const float* __restrict__ bias, float* __restrict__ C,
             int M, int N, int K) {
  const int n0 = blockIdx.x * 128;
  const int m0 = blockIdx.y * 128;
  const int t  = threadIdx.x;
  const int tx = t & 15, ty = t >> 4;

  __shared__ float As[16][128];
  __shared__ float Bs[16][128];

  float acc[8][8];
#pragma unroll
  for (int i = 0; i < 8; ++i)
#pragma unroll
    for (int j = 0; j < 8; ++j) acc[i][j] = 0.f;

  for (int kb = 0; kb < K; kb += 16) {
#pragma unroll
    for (int it = 0; it < 2; ++it) {
      int idx = t + it * 256;           // 0..511
      int row = idx >> 2;               // 0..127
      int k4  = (idx & 3) << 2;         // 0,4,8,12
      float4 a = *(const float4*)&A[(size_t)(m0 + row) * K + kb + k4];
      float4 b = *(const float4*)&B[(size_t)(n0 + row) * K + kb + k4];
      As[k4+0][row] = a.x; As[k4+1][row] = a.y; As[k4+2][row] = a.z; As[k4+3][row] = a.w;
      Bs[k4+0][row] = b.x; Bs[k4+1][row] = b.y; Bs[k4+2][row] = b.z; Bs[k4+3][row] = b.w;
    }
    __syncthreads();
#pragma unroll
    for (int k = 0; k < 16; ++k) {
      float4 a0 = *(const float4*)&As[k][4*ty];
      float4 a1 = *(const float4*)&As[k][4*ty + 64];
      float4 b0 = *(const float4*)&Bs[k][4*tx];
      float4 b1 = *(const float4*)&Bs[k][4*tx + 64];
      float av[8] = {a0.x,a0.y,a0.z,a0.w,a1.x,a1.y,a1.z,a1.w};
      float bv[8] = {b0.x,b0.y,b0.z,b0.w,b1.x,b1.y,b1.z,b1.w};
#pragma unroll
      for (int i = 0; i < 8; ++i)
#pragma unroll
        for (int j = 0; j < 8; ++j)
          acc[i][j] = fmaf(av[i], bv[j], acc[i][j]);
    }
    __syncthreads();
  }
#pragma unroll
  for (int i = 0; i < 8; ++i) {
    int row = m0 + 4*ty + (i & 3) + (i >> 2) * 64;
#pragma unroll
    for (int jg = 0; jg < 2; ++jg) {
      int col = n0 + 4*tx + jg * 64;
      float4 r;
      r.x = acc[i][jg*4+0]; r.y = acc[i][jg*4+1];
      r.z = acc[i][jg*4+2]; r.w = acc[i][jg*4+3];
      if (BIAS) {
        r.x += bias[col+0]; r.y += bias[col+1];
        r.z += bias[col+2]; r.w += bias[col+3];
      }
      *(float4*)&C[(size_t)row * N + col] = r;
    }
  }
}

// ---------------------------------------------------------------------------
// Fused per-head-dim RMSNorm (eps=1e-6) + RoPE, in place on q and k rows.
// One block per (qk, head, position); 128 threads = head_dim.
// ---------------------------------------------------------------------------
__global__ __launch_bounds__(128)
void norm_rope(float* __restrict__ qkv, const float* __restrict__ pe,
               const float* __restrict__ q_scale, const float* __restrict__ k_scale) {
  const int l  = blockIdx.x;           // position
  const int hh = blockIdx.y;           // qk*16 + h
  const int qk = hh >> 4;
  const int h  = hh & 15;
  const int d  = threadIdx.x;          // 0..127
  float* row = qkv + (size_t)l * TDIM + qk * DIM + h * HD;
  const float* scale = qk ? k_scale : q_scale;

  float v  = row[d];
  float sq = v * v;
#pragma unroll
  for (int o = 32; o > 0; o >>= 1) sq += __shfl_xor(sq, o);
  __shared__ float wsum[2];
  if ((d & 63) == 0) wsum[d >> 6] = sq;
  __syncthreads();
  float rrms = rsqrtf((wsum[0] + wsum[1]) * (1.f / 128.f) + 1e-6f);
  __shared__ float nb[128];
  nb[d] = v * rrms * scale[d];
  __syncthreads();
  int i = d >> 1, c = d & 1;
  const float* p = pe + ((size_t)(l * 64 + i) * 2 + c) * 2;
  row[d] = p[0] * nb[2*i] + p[1] * nb[2*i + 1];
}

// ---------------------------------------------------------------------------
// Flash attention, fp32. One block per (head, 64-row Q tile); 256 threads.
// BQ=BK=64. S micro-tile 4x4 (rows ty+16i, cols tx+16j), PV micro-tile 4x8.
// Strided ownership keeps every LDS read <=2-way bank aliased (free).
// Writes attn_out in [L][H*HD] layout (already transposed for proj GEMM).
// ---------------------------------------------------------------------------
__global__ __launch_bounds__(256)
void attn(const float* __restrict__ qkv, float* __restrict__ out) {
  const int q0 = blockIdx.x * 64;
  const int h  = blockIdx.y;
  const int t  = threadIdx.x;
  const int tx = t & 15, ty = t >> 4;

  __shared__ float Qs[64][130];
  __shared__ float Ks[64][130];
  __shared__ float Vs[64][130];
  __shared__ float Ss[64][65];
  __shared__ float m_s[64], l_s[64], alpha_s[64];
  __shared__ float red[64][4];

  const float scale = 0.08838834764831845f;  // 1/sqrt(128)

#pragma unroll
  for (int it = 0; it < 8; ++it) {
    int idx = t + it * 256;          // 0..2047
    int row = idx >> 5;              // 0..63
    int c4  = (idx & 31) << 2;       // 0..124
    *(float4*)&Qs[row][c4] =
        *(const float4*)&qkv[(size_t)(q0 + row) * TDIM + h * HD + c4];
  }
  if (t < 64) { m_s[t] = -1e30f; l_s[t] = 0.f; }

  float O[4][8];
#pragma unroll
  for (int i = 0; i < 4; ++i)
#pragma unroll
    for (int j = 0; j < 8; ++j) O[i][j] = 0.f;

  __syncthreads();

  for (int kt = 0; kt < L_SEQ / 64; ++kt) {
    int k0 = kt * 64;
#pragma unroll
    for (int it = 0; it < 8; ++it) {
      int idx = t + it * 256;
      int row = idx >> 5;
      int c4  = (idx & 31) << 2;
      const float* src = &qkv[(size_t)(k0 + row) * TDIM + h * HD + c4];
      *(float4*)&Ks[row][c4] = *(const float4*)(src + DIM);
      *(float4*)&Vs[row][c4] = *(const float4*)(src + 2 * DIM);
    }
    __syncthreads();

    // S = Q K^T
    float acc[4][4];
#pragma unroll
    for (int i = 0; i < 4; ++i)
#pragma unroll
      for (int j = 0; j < 4; ++j) acc[i][j] = 0.f;

    for (int d = 0; d < HD; d += 2) {
      float2 a[4], b[4];
#pragma unroll
      for (int i = 0; i < 4; ++i) a[i] = *(const float2*)&Qs[ty + 16*i][d];
#pragma unroll
      for (int j = 0; j < 4; ++j) b[j] = *(const float2*)&Ks[tx + 16*j][d];
#pragma unroll
      for (int i = 0; i < 4; ++i)
#pragma unroll
        for (int j = 0; j < 4; ++j)
          acc[i][j] = fmaf(a[i].x, b[j].x, fmaf(a[i].y, b[j].y, acc[i][j]));
    }
#pragma unroll
    for (int i = 0; i < 4; ++i)
#pragma unroll
      for (int j = 0; j < 4; ++j)
        Ss[ty + 16*i][tx + 16*j] = acc[i][j] * scale;
    __syncthreads();

    // tile row max (4 partials per row)
    {
      int r = t & 63, ch = t >> 6;
      float mx = -1e30f;
#pragma unroll
      for (int cc = 0; cc < 16; ++cc) mx = fmaxf(mx, Ss[r][ch*16 + cc]);
      red[r][ch] = mx;
    }
    __syncthreads();
    if (t < 64) {
      float mt = fmaxf(fmaxf(red[t][0], red[t][1]), fmaxf(red[t][2], red[t][3]));
      float mn = fmaxf(m_s[t], mt);
      alpha_s[t] = __expf(m_s[t] - mn);
      m_s[t] = mn;
    }
    __syncthreads();
    // P = exp(S - m), partial row sums
    {
      int r = t & 63, ch = t >> 6;
      float mn = m_s[r], sum = 0.f;
#pragma unroll
      for (int cc = 0; cc < 16; ++cc) {
        float p = __expf(Ss[r][ch*16 + cc] - mn);
        Ss[r][ch*16 + cc] = p;
        sum += p;
      }
      red[r][ch] = sum;
    }
    __syncthreads();
    if (t < 64)
      l_s[t] = l_s[t] * alpha_s[t] + red[t][0] + red[t][1] + red[t][2] + red[t][3];

    // O = O*alpha + P V
    float al[4];
#pragma unroll
    for (int i = 0; i < 4; ++i) al[i] = alpha_s[ty + 16*i];
#pragma unroll
    for (int i = 0; i < 4; ++i)
#pragma unroll
      for (int j = 0; j < 8; ++j) O[i][j] *= al[i];

    for (int kk = 0; kk < 64; ++kk) {
      float p[4];
#pragma unroll
      for (int i = 0; i < 4; ++i) p[i] = Ss[ty + 16*i][kk];
#pragma unroll
      for (int j = 0; j < 8; ++j) {
        float v = Vs[kk][tx + 16*j];
#pragma unroll
        for (int i = 0; i < 4; ++i) O[i][j] = fmaf(p[i], v, O[i][j]);
      }
    }
    __syncthreads();
  }

  float linv[4];
#pragma unroll
  for (int i = 0; i < 4; ++i) linv[i] = 1.f / l_s[ty + 16*i];
#pragma unroll
  for (int i = 0; i < 4; ++i) {
    size_t rowoff = (size_t)(q0 + ty + 16*i) * DIM + h * HD;
#pragma unroll
    for (int j = 0; j < 8; ++j)
      out[rowoff + tx + 16*j] = O[i][j] * linv[i];
  }
}

// ---------------------------------------------------------------------------
extern "C" void kernel_launch(void* const* d_in, const int* in_sizes, int n_in,
                              void* d_out, int out_size, void* d_ws, size_t ws_size,
                              hipStream_t stream) {
  const float* x       = (const float*)d_in[0];
  const float* pe      = (const float*)d_in[1];
  const float* qkv_w   = (const float*)d_in[2];
  const float* q_scale = (const float*)d_in[3];
  const float* k_scale = (const float*)d_in[4];
  const float* proj_w  = (const float*)d_in[5];
  const float* proj_b  = (const float*)d_in[6];
  float* out = (float*)d_out;

  float* qkv      = (float*)d_ws;                       // [2048][6144]
  float* attn_out = qkv + (size_t)L_SEQ * TDIM;         // [2048][2048]

  // 1) qkv = x @ qkv_w^T
  gemm_nt<false><<<dim3(TDIM / 128, L_SEQ / 128), 256, 0, stream>>>(
      x, qkv_w, nullptr, qkv, L_SEQ, TDIM, DIM);

  // 2) RMSNorm + RoPE on q,k (in place)
  norm_rope<<<dim3(L_SEQ, 2 * NH), 128, 0, stream>>>(qkv, pe, q_scale, k_scale);

  // 3) flash attention -> attn_out in [L][H*HD] layout
  attn<<<dim3(L_SEQ / 64, NH), 256, 0, stream>>>(qkv, attn_out);

  // 4) out = attn_out @ proj_w^T + proj_b
  gemm_nt<true><<<dim3(DIM / 128, DIM / 128), 256, 0, stream>>>(
      attn_out, proj_w, proj_b, out, L_SEQ, DIM, DIM);
}

// Round 2
// 1159.384 us; speedup vs baseline: 1.6276x; 1.6276x over previous
//
#include <hip/hip_runtime.h>
#include <hip/hip_bf16.h>
#include <math.h>

#define L_SEQ 2048
#define DIM   2048
#define NH    16
#define HD    128

typedef __attribute__((ext_vector_type(8))) short short8;
typedef __attribute__((ext_vector_type(4))) float f32x4;

// ---------------------------------------------------------------------------
// QKV GEMM (fp32 VALU): C = x[2048][2048] * qkv_w[6144][2048]^T.
// Split output: cols [0,4096) -> fp32 qk buffer (row stride 4096),
//               cols [4096,6144) -> bf16 Vb[l][2048].
// ---------------------------------------------------------------------------
__global__ __launch_bounds__(256)
void gemm_qkv(const float* __restrict__ A, const float* __restrict__ B,
              float* __restrict__ Cqk, __hip_bfloat16* __restrict__ Vb) {
  const int K = DIM, n0 = blockIdx.x * 128, m0 = blockIdx.y * 128;
  const int t = threadIdx.x, tx = t & 15, ty = t >> 4;
  __shared__ float As[16][128];
  __shared__ float Bs[16][128];
  float acc[8][8];
#pragma unroll
  for (int i = 0; i < 8; ++i)
#pragma unroll
    for (int j = 0; j < 8; ++j) acc[i][j] = 0.f;

  for (int kb = 0; kb < K; kb += 16) {
#pragma unroll
    for (int it = 0; it < 2; ++it) {
      int idx = t + it * 256, row = idx >> 2, k4 = (idx & 3) << 2;
      float4 a = *(const float4*)&A[(size_t)(m0 + row) * K + kb + k4];
      float4 b = *(const float4*)&B[(size_t)(n0 + row) * K + kb + k4];
      As[k4+0][row] = a.x; As[k4+1][row] = a.y; As[k4+2][row] = a.z; As[k4+3][row] = a.w;
      Bs[k4+0][row] = b.x; Bs[k4+1][row] = b.y; Bs[k4+2][row] = b.z; Bs[k4+3][row] = b.w;
    }
    __syncthreads();
#pragma unroll
    for (int k = 0; k < 16; ++k) {
      float4 a0 = *(const float4*)&As[k][4*ty];
      float4 a1 = *(const float4*)&As[k][4*ty + 64];
      float4 b0 = *(const float4*)&Bs[k][4*tx];
      float4 b1 = *(const float4*)&Bs[k][4*tx + 64];
      float av[8] = {a0.x,a0.y,a0.z,a0.w,a1.x,a1.y,a1.z,a1.w};
      float bv[8] = {b0.x,b0.y,b0.z,b0.w,b1.x,b1.y,b1.z,b1.w};
#pragma unroll
      for (int i = 0; i < 8; ++i)
#pragma unroll
        for (int j = 0; j < 8; ++j)
          acc[i][j] = fmaf(av[i], bv[j], acc[i][j]);
    }
    __syncthreads();
  }
#pragma unroll
  for (int i = 0; i < 8; ++i) {
    int row = m0 + 4*ty + (i & 3) + (i >> 2) * 64;
#pragma unroll
    for (int jg = 0; jg < 2; ++jg) {
      int col = n0 + 4*tx + jg * 64;
      float4 r;
      r.x = acc[i][jg*4+0]; r.y = acc[i][jg*4+1];
      r.z = acc[i][jg*4+2]; r.w = acc[i][jg*4+3];
      if (n0 < 4096) {
        *(float4*)&Cqk[(size_t)row * 4096 + col] = r;
      } else {
        __hip_bfloat16 b0 = __float2bfloat16(r.x), b1 = __float2bfloat16(r.y);
        __hip_bfloat16 b2 = __float2bfloat16(r.z), b3 = __float2bfloat16(r.w);
        ushort4 pv = make_ushort4(*(unsigned short*)&b0, *(unsigned short*)&b1,
                                  *(unsigned short*)&b2, *(unsigned short*)&b3);
        *(ushort4*)&Vb[(size_t)row * DIM + col - 4096] = pv;
      }
    }
  }
}

// ---------------------------------------------------------------------------
// RMSNorm + RoPE on q,k; outputs bf16 head-major Qb/Kb[h][l][d].
// Q additionally folded with 1/sqrt(HD).
// ---------------------------------------------------------------------------
__global__ __launch_bounds__(128)
void norm_rope(const float* __restrict__ qk, const float* __restrict__ pe,
               const float* __restrict__ q_scale, const float* __restrict__ k_scale,
               __hip_bfloat16* __restrict__ Qb, __hip_bfloat16* __restrict__ Kb) {
  const int l  = blockIdx.x;
  const int hh = blockIdx.y;
  const int qk_sel = hh >> 4;
  const int h  = hh & 15;
  const int d  = threadIdx.x;
  const float* row = qk + (size_t)l * 4096 + qk_sel * DIM + h * HD;
  const float* scale = qk_sel ? k_scale : q_scale;

  float v  = row[d];
  float sq = v * v;
#pragma unroll
  for (int o = 32; o > 0; o >>= 1) sq += __shfl_xor(sq, o);
  __shared__ float wsum[2];
  if ((d & 63) == 0) wsum[d >> 6] = sq;
  __syncthreads();
  float rrms = rsqrtf((wsum[0] + wsum[1]) * (1.f / 128.f) + 1e-6f);
  __shared__ float nb[128];
  nb[d] = v * rrms * scale[d];
  __syncthreads();
  int i = d >> 1, c = d & 1;
  const float* p = pe + ((size_t)(l * 64 + i) * 2 + c) * 2;
  float res = p[0] * nb[2*i] + p[1] * nb[2*i + 1];
  size_t o_idx = ((size_t)h * L_SEQ + l) * HD + d;
  if (qk_sel == 0) Qb[o_idx] = __float2bfloat16(res * 0.08838834764831845f);
  else             Kb[o_idx] = __float2bfloat16(res);
}

// ---------------------------------------------------------------------------
// Transpose V: Vb[l][h*128+d] bf16 -> Vt[h][d][l] bf16.
// ---------------------------------------------------------------------------
__global__ __launch_bounds__(256)
void v_transpose(const __hip_bfloat16* __restrict__ Vb, __hip_bfloat16* __restrict__ Vt) {
  const int l0 = blockIdx.x * 64;
  const int h  = blockIdx.y;
  const int t  = threadIdx.x;
  __shared__ __align__(16) __hip_bfloat16 T[128][72];
#pragma unroll
  for (int it = 0; it < 4; ++it) {
    int idx = t + it * 256;          // 0..1023 chunks of 8
    int row = idx >> 4;              // l-offset 0..63
    int c8  = (idx & 15) * 8;        // d 0..120
    short8 v = *(const short8*)&Vb[(size_t)(l0 + row) * DIM + h * HD + c8];
#pragma unroll
    for (int j = 0; j < 8; ++j) *(short*)&T[c8 + j][row] = v[j];
  }
  __syncthreads();
#pragma unroll
  for (int it = 0; it < 4; ++it) {
    int idx = t + it * 256;
    int d = idx >> 3, c8 = (idx & 7) * 8;
    *(short8*)(Vt + ((size_t)h * HD + d) * L_SEQ + l0 + c8) = *(const short8*)&T[d][c8];
  }
}

// ---------------------------------------------------------------------------
// Flash attention, bf16 MFMA. Block = 4 waves, BQ=128 (32 q-rows/wave), BK=64.
// S = Q*K^T and O = P*Vt^T via mfma_f32_16x16x32_bf16 (NT form, both operands
// row-major k-consecutive). Softmax fp32 on C-layout regs; P via LDS.
// Output bf16 [l][h*128+d]. Q pre-scaled by 1/sqrt(HD).
// ---------------------------------------------------------------------------
__global__ __launch_bounds__(256, 1)
void attn_mfma(const __hip_bfloat16* __restrict__ Qb,
               const __hip_bfloat16* __restrict__ Kb,
               const __hip_bfloat16* __restrict__ Vt,
               __hip_bfloat16* __restrict__ out) {
  const int q0 = blockIdx.x * 128;
  const int h  = blockIdx.y;
  const int t  = threadIdx.x;
  const int lane = t & 63, w = t >> 6;
  const int l15 = lane & 15, quad = lane >> 4;

  __shared__ __align__(16) __hip_bfloat16 Ks[64][136];   // +8 pad: 2-way only
  __shared__ __align__(16) __hip_bfloat16 Vs[128][72];   // [d][l]
  __shared__ __align__(16) __hip_bfloat16 Ps[128][72];   // [q][kv]

  // Q fragments (registers): rows w*32 + mt*16 + l15, k = ks*32 + quad*8
  short8 aq[2][4];
  const __hip_bfloat16* qbase = Qb + ((size_t)h * L_SEQ + q0 + w * 32) * HD;
#pragma unroll
  for (int mt = 0; mt < 2; ++mt)
#pragma unroll
    for (int ks = 0; ks < 4; ++ks)
      aq[mt][ks] = *(const short8*)(qbase + (size_t)(mt*16 + l15) * HD + ks*32 + quad*8);

  f32x4 o[2][8];
#pragma unroll
  for (int mt = 0; mt < 2; ++mt)
#pragma unroll
    for (int n2 = 0; n2 < 8; ++n2) o[mt][n2] = (f32x4){0.f, 0.f, 0.f, 0.f};
  float m_run[2][4], l_run[2][4];
#pragma unroll
  for (int mt = 0; mt < 2; ++mt)
#pragma unroll
    for (int r = 0; r < 4; ++r) { m_run[mt][r] = -1e30f; l_run[mt][r] = 0.f; }

  const __hip_bfloat16* kbase = Kb + (size_t)h * L_SEQ * HD;
  const __hip_bfloat16* vbase = Vt + (size_t)h * HD * L_SEQ;

  for (int kt = 0; kt < L_SEQ / 64; ++kt) {
    const int k0 = kt * 64;
#pragma unroll
    for (int it = 0; it < 4; ++it) {           // stage K tile: 64x128 bf16
      int idx = t + it * 256, row = idx >> 4, c8 = (idx & 15) * 8;
      *(short8*)&Ks[row][c8] = *(const short8*)(kbase + (size_t)(k0 + row) * HD + c8);
    }
#pragma unroll
    for (int it = 0; it < 4; ++it) {           // stage Vt tile: 128 d x 64 l
      int idx = t + it * 256, d = idx >> 3, c8 = (idx & 7) * 8;
      *(short8*)&Vs[d][c8] = *(const short8*)(vbase + (size_t)d * L_SEQ + k0 + c8);
    }
    __syncthreads();

    // ---- S = Q K^T : 32 MFMA / wave ----
    f32x4 s[2][4];
#pragma unroll
    for (int mt = 0; mt < 2; ++mt)
#pragma unroll
      for (int nt = 0; nt < 4; ++nt) s[mt][nt] = (f32x4){0.f, 0.f, 0.f, 0.f};
#pragma unroll
    for (int ks = 0; ks < 4; ++ks) {
      short8 bk[4];
#pragma unroll
      for (int nt = 0; nt < 4; ++nt)
        bk[nt] = *(const short8*)&Ks[nt*16 + l15][ks*32 + quad*8];
#pragma unroll
      for (int mt = 0; mt < 2; ++mt)
#pragma unroll
        for (int nt = 0; nt < 4; ++nt)
          s[mt][nt] = __builtin_amdgcn_mfma_f32_16x16x32_bf16(aq[mt][ks], bk[nt], s[mt][nt], 0, 0, 0);
    }

    // ---- online softmax (rows: w*32 + mt*16 + quad*4 + r) ----
#pragma unroll
    for (int mt = 0; mt < 2; ++mt) {
      float alpha[4];
#pragma unroll
      for (int r = 0; r < 4; ++r) {
        float rm = fmaxf(fmaxf(s[mt][0][r], s[mt][1][r]), fmaxf(s[mt][2][r], s[mt][3][r]));
#pragma unroll
        for (int off = 1; off < 16; off <<= 1) rm = fmaxf(rm, __shfl_xor(rm, off));
        float mnew = fmaxf(m_run[mt][r], rm);
        alpha[r] = __expf(m_run[mt][r] - mnew);
        m_run[mt][r] = mnew;
        float sum = 0.f;
#pragma unroll
        for (int nt = 0; nt < 4; ++nt) {
          float p = __expf(s[mt][nt][r] - mnew);
          s[mt][nt][r] = p;
          sum += p;
        }
#pragma unroll
        for (int off = 1; off < 16; off <<= 1) sum += __shfl_xor(sum, off);
        l_run[mt][r] = l_run[mt][r] * alpha[r] + sum;
      }
#pragma unroll
      for (int n2 = 0; n2 < 8; ++n2)
#pragma unroll
        for (int r = 0; r < 4; ++r) o[mt][n2][r] *= alpha[r];
      // P -> LDS (C-layout scatter: fixed col, strided rows)
#pragma unroll
      for (int nt = 0; nt < 4; ++nt)
#pragma unroll
        for (int r = 0; r < 4; ++r)
          Ps[w*32 + mt*16 + quad*4 + r][nt*16 + l15] = __float2bfloat16(s[mt][nt][r]);
    }
    __syncthreads();

    // ---- O += P Vt^T : 32 MFMA / wave ----
#pragma unroll
    for (int ks2 = 0; ks2 < 2; ++ks2) {
      short8 ap[2];
#pragma unroll
      for (int mt = 0; mt < 2; ++mt)
        ap[mt] = *(const short8*)&Ps[w*32 + mt*16 + l15][ks2*32 + quad*8];
#pragma unroll
      for (int n2 = 0; n2 < 8; ++n2) {
        short8 bv = *(const short8*)&Vs[n2*16 + l15][ks2*32 + quad*8];
#pragma unroll
        for (int mt = 0; mt < 2; ++mt)
          o[mt][n2] = __builtin_amdgcn_mfma_f32_16x16x32_bf16(ap[mt], bv, o[mt][n2], 0, 0, 0);
      }
    }
    __syncthreads();
  }

  // epilogue: out[q][h*128 + d] bf16
#pragma unroll
  for (int mt = 0; mt < 2; ++mt)
#pragma unroll
    for (int r = 0; r < 4; ++r) {
      float inv = 1.f / l_run[mt][r];
      int q = q0 + w*32 + mt*16 + quad*4 + r;
#pragma unroll
      for (int n2 = 0; n2 < 8; ++n2)
        out[(size_t)q * DIM + h*HD + n2*16 + l15] = __float2bfloat16(o[mt][n2][r] * inv);
    }
}

// ---------------------------------------------------------------------------
// Proj GEMM: C[2048][2048] = attn_out(bf16)[2048][2048] * proj_w^T + bias.
// A converted bf16->fp32 at LDS staging; inner loop identical to gemm_qkv.
// ---------------------------------------------------------------------------
__global__ __launch_bounds__(256)
void gemm_proj(const __hip_bfloat16* __restrict__ A, const float* __restrict__ B,
               const float* __restrict__ bias, float* __restrict__ C) {
  const int K = DIM, N = DIM, n0 = blockIdx.x * 128, m0 = blockIdx.y * 128;
  const int t = threadIdx.x, tx = t & 15, ty = t >> 4;
  __shared__ float As[16][128];
  __shared__ float Bs[16][128];
  float acc[8][8];
#pragma unroll
  for (int i = 0; i < 8; ++i)
#pragma unroll
    for (int j = 0; j < 8; ++j) acc[i][j] = 0.f;

  for (int kb = 0; kb < K; kb += 16) {
    {
      int row = t >> 1, k8 = (t & 1) * 8;
      short8 a8 = *(const short8*)&A[(size_t)(m0 + row) * K + kb + k8];
#pragma unroll
      for (int j = 0; j < 8; ++j) {
        unsigned int u = ((unsigned int)(unsigned short)a8[j]) << 16;
        As[k8 + j][row] = __uint_as_float(u);
      }
    }
#pragma unroll
    for (int it = 0; it < 2; ++it) {
      int idx = t + it * 256, row = idx >> 2, k4 = (idx & 3) << 2;
      float4 b = *(const float4*)&B[(size_t)(n0 + row) * K + kb + k4];
      Bs[k4+0][row] = b.x; Bs[k4+1][row] = b.y; Bs[k4+2][row] = b.z; Bs[k4+3][row] = b.w;
    }
    __syncthreads();
#pragma unroll
    for (int k = 0; k < 16; ++k) {
      float4 a0 = *(const float4*)&As[k][4*ty];
      float4 a1 = *(const float4*)&As[k][4*ty + 64];
      float4 b0 = *(const float4*)&Bs[k][4*tx];
      float4 b1 = *(const float4*)&Bs[k][4*tx + 64];
      float av[8] = {a0.x,a0.y,a0.z,a0.w,a1.x,a1.y,a1.z,a1.w};
      float bv[8] = {b0.x,b0.y,b0.z,b0.w,b1.x,b1.y,b1.z,b1.w};
#pragma unroll
      for (int i = 0; i < 8; ++i)
#pragma unroll
        for (int j = 0; j < 8; ++j)
          acc[i][j] = fmaf(av[i], bv[j], acc[i][j]);
    }
    __syncthreads();
  }
#pragma unroll
  for (int i = 0; i < 8; ++i) {
    int row = m0 + 4*ty + (i & 3) + (i >> 2) * 64;
#pragma unroll
    for (int jg = 0; jg < 2; ++jg) {
      int col = n0 + 4*tx + jg * 64;
      float4 r;
      r.x = acc[i][jg*4+0] + bias[col+0];
      r.y = acc[i][jg*4+1] + bias[col+1];
      r.z = acc[i][jg*4+2] + bias[col+2];
      r.w = acc[i][jg*4+3] + bias[col+3];
      *(float4*)&C[(size_t)row * N + col] = r;
    }
  }
}

// ---------------------------------------------------------------------------
extern "C" void kernel_launch(void* const* d_in, const int* in_sizes, int n_in,
                              void* d_out, int out_size, void* d_ws, size_t ws_size,
                              hipStream_t stream) {
  const float* x       = (const float*)d_in[0];
  const float* pe      = (const float*)d_in[1];
  const float* qkv_w   = (const float*)d_in[2];
  const float* q_scale = (const float*)d_in[3];
  const float* k_scale = (const float*)d_in[4];
  const float* proj_w  = (const float*)d_in[5];
  const float* proj_b  = (const float*)d_in[6];
  float* out = (float*)d_out;

  // Workspace layout (total exactly 67,108,864 B = round-1 proven footprint):
  //   [0, 33.5M)   qk fp32 [2048][4096]      (dead after norm_rope; attn_out aliases it)
  //   [33.5M, +8M) Vb bf16 [2048][2048]
  //   then Qb, Kb, Vt bf16 (each 8,388,608 B)
  float* qk_f32 = (float*)d_ws;
  char* basep = (char*)d_ws + (size_t)33554432;
  __hip_bfloat16* Vb = (__hip_bfloat16*)basep;
  __hip_bfloat16* Qb = (__hip_bfloat16*)(basep + 8388608);
  __hip_bfloat16* Kb = (__hip_bfloat16*)(basep + 2 * 8388608);
  __hip_bfloat16* Vt = (__hip_bfloat16*)(basep + 3 * 8388608);
  __hip_bfloat16* attn_out = (__hip_bfloat16*)d_ws;   // aliases dead qk_f32

  gemm_qkv<<<dim3(6144 / 128, L_SEQ / 128), 256, 0, stream>>>(x, qkv_w, qk_f32, Vb);
  norm_rope<<<dim3(L_SEQ, 2 * NH), 128, 0, stream>>>(qk_f32, pe, q_scale, k_scale, Qb, Kb);
  v_transpose<<<dim3(L_SEQ / 64, NH), 256, 0, stream>>>(Vb, Vt);
  attn_mfma<<<dim3(L_SEQ / 128, NH), 256, 0, stream>>>(Qb, Kb, Vt, attn_out);
  gemm_proj<<<dim3(DIM / 128, DIM / 128), 256, 0, stream>>>(attn_out, proj_w, proj_b, out);
}

// Round 3
// 449.188 us; speedup vs baseline: 4.2010x; 2.5811x over previous
//
#include <hip/hip_runtime.h>
#include <hip/hip_bf16.h>
#include <math.h>

#define L_SEQ 2048
#define DIM   2048
#define NH    16
#define HD    128
#define TDIM  6144

typedef __attribute__((ext_vector_type(8))) short short8;
typedef __attribute__((ext_vector_type(4))) float f32x4;

// async global->LDS, 16 B per lane. LDS dest = wave-uniform base + lane*16.
__device__ __forceinline__ void gl_lds16(const void* g, void* l) {
  __builtin_amdgcn_global_load_lds(
      (const __attribute__((address_space(1))) unsigned int*)g,
      (__attribute__((address_space(3))) unsigned int*)l, 16, 0, 0);
}

__device__ __forceinline__ short bf16bits(float x) {
  __hip_bfloat16 h = __float2bfloat16(x);
  return *(short*)&h;
}

// ---------------------------------------------------------------------------
// fp32 -> bf16 cast, 8 elements/thread.
// ---------------------------------------------------------------------------
__global__ __launch_bounds__(256)
void cast_bf16(const float* __restrict__ in, __hip_bfloat16* __restrict__ out, int n) {
  int i = (blockIdx.x * 256 + threadIdx.x) * 8;
  if (i >= n) return;
  float4 a = *(const float4*)(in + i);
  float4 b = *(const float4*)(in + i + 4);
  short8 o;
  o[0] = bf16bits(a.x); o[1] = bf16bits(a.y); o[2] = bf16bits(a.z); o[3] = bf16bits(a.w);
  o[4] = bf16bits(b.x); o[5] = bf16bits(b.y); o[6] = bf16bits(b.z); o[7] = bf16bits(b.w);
  *(short8*)(out + i) = o;
}

// ---------------------------------------------------------------------------
// bf16 MFMA GEMM (m97 structure): C[M][N] = A[M][K] * B[N][K]^T.
// 128x128 tile, BK=32, 4 waves, 4x4 16x16x32 MFMA tiles per wave,
// global_load_lds width-16 staging. OUT_MODE 0: bf16 C. 1: fp32 C + bias.
// ---------------------------------------------------------------------------
template<int OUT_MODE>
__global__ __launch_bounds__(256)
void gemm_mfma(const __hip_bfloat16* __restrict__ A, const __hip_bfloat16* __restrict__ B,
               const float* __restrict__ bias, void* __restrict__ Cout,
               int M, int N, int K) {
  const int n0 = blockIdx.x * 128, m0 = blockIdx.y * 128;
  const int t = threadIdx.x, lane = t & 63, w = t >> 6;
  const int l15 = lane & 15, quad = lane >> 4;
  const int wm = (w & 1) * 64, wn = (w >> 1) * 64;

  __shared__ __align__(16) __hip_bfloat16 As[128 * 32];
  __shared__ __align__(16) __hip_bfloat16 Bs[128 * 32];

  f32x4 acc[4][4];
#pragma unroll
  for (int mt = 0; mt < 4; ++mt)
#pragma unroll
    for (int nt = 0; nt < 4; ++nt) acc[mt][nt] = (f32x4){0.f, 0.f, 0.f, 0.f};

  const int arow  = lane >> 2;        // 0..15 row within 16-row group
  const int acol8 = (lane & 3) * 8;   // k-offset (8 bf16 = 16 B)
  const __hip_bfloat16* Ab = A + (size_t)(m0 + w * 16 + arow) * K + acol8;
  const __hip_bfloat16* Bb = B + (size_t)(n0 + w * 16 + arow) * K + acol8;
  __hip_bfloat16* As_base = As + (size_t)(w * 16) * 32;  // lane*16B added by HW
  __hip_bfloat16* Bs_base = Bs + (size_t)(w * 16) * 32;

  for (int kb = 0; kb < K; kb += 32) {
    gl_lds16(Ab + kb,                As_base);
    gl_lds16(Ab + kb + (size_t)64*K, As_base + 64 * 32);
    gl_lds16(Bb + kb,                Bs_base);
    gl_lds16(Bb + kb + (size_t)64*K, Bs_base + 64 * 32);
    __syncthreads();

    short8 am[4], bn[4];
#pragma unroll
    for (int mt = 0; mt < 4; ++mt)
      am[mt] = *(const short8*)&As[(size_t)(wm + mt*16 + l15) * 32 + quad * 8];
#pragma unroll
    for (int nt = 0; nt < 4; ++nt)
      bn[nt] = *(const short8*)&Bs[(size_t)(wn + nt*16 + l15) * 32 + quad * 8];
#pragma unroll
    for (int mt = 0; mt < 4; ++mt)
#pragma unroll
      for (int nt = 0; nt < 4; ++nt)
        acc[mt][nt] = __builtin_amdgcn_mfma_f32_16x16x32_bf16(am[mt], bn[nt], acc[mt][nt], 0, 0, 0);
    __syncthreads();
  }

  // epilogue: C/D layout col=lane&15, row=quad*4+reg
#pragma unroll
  for (int mt = 0; mt < 4; ++mt) {
#pragma unroll
    for (int nt = 0; nt < 4; ++nt) {
      int col = n0 + wn + nt * 16 + l15;
#pragma unroll
      for (int r = 0; r < 4; ++r) {
        int row = m0 + wm + mt * 16 + quad * 4 + r;
        if (OUT_MODE == 0) {
          ((__hip_bfloat16*)Cout)[(size_t)row * N + col] = __float2bfloat16(acc[mt][nt][r]);
        } else {
          ((float*)Cout)[(size_t)row * N + col] = acc[mt][nt][r] + bias[col];
        }
      }
    }
  }
}

// ---------------------------------------------------------------------------
// RMSNorm + RoPE on q,k (bf16 in, fp32 math); outputs bf16 head-major.
// Q folded with 1/sqrt(HD).
// ---------------------------------------------------------------------------
__global__ __launch_bounds__(128)
void norm_rope(const __hip_bfloat16* __restrict__ qkv_b, const float* __restrict__ pe,
               const float* __restrict__ q_scale, const float* __restrict__ k_scale,
               __hip_bfloat16* __restrict__ Qb, __hip_bfloat16* __restrict__ Kb) {
  const int l  = blockIdx.x;
  const int hh = blockIdx.y;
  const int qk_sel = hh >> 4;
  const int h  = hh & 15;
  const int d  = threadIdx.x;
  const __hip_bfloat16* row = qkv_b + (size_t)l * TDIM + qk_sel * DIM + h * HD;
  const float* scale = qk_sel ? k_scale : q_scale;

  float v  = __bfloat162float(row[d]);
  float sq = v * v;
#pragma unroll
  for (int o = 32; o > 0; o >>= 1) sq += __shfl_xor(sq, o);
  __shared__ float wsum[2];
  if ((d & 63) == 0) wsum[d >> 6] = sq;
  __syncthreads();
  float rrms = rsqrtf((wsum[0] + wsum[1]) * (1.f / 128.f) + 1e-6f);
  __shared__ float nb[128];
  nb[d] = v * rrms * scale[d];
  __syncthreads();
  int i = d >> 1, c = d & 1;
  const float* p = pe + ((size_t)(l * 64 + i) * 2 + c) * 2;
  float res = p[0] * nb[2*i] + p[1] * nb[2*i + 1];
  size_t o_idx = ((size_t)h * L_SEQ + l) * HD + d;
  if (qk_sel == 0) Qb[o_idx] = __float2bfloat16(res * 0.08838834764831845f);
  else             Kb[o_idx] = __float2bfloat16(res);
}

// ---------------------------------------------------------------------------
// Transpose V (cols 4096..6143 of qkv_b) -> Vt[h][d][l] bf16.
// ---------------------------------------------------------------------------
__global__ __launch_bounds__(256)
void v_transpose(const __hip_bfloat16* __restrict__ qkv_b, __hip_bfloat16* __restrict__ Vt) {
  const int l0 = blockIdx.x * 64;
  const int h  = blockIdx.y;
  const int t  = threadIdx.x;
  __shared__ __align__(16) __hip_bfloat16 T[128][72];
#pragma unroll
  for (int it = 0; it < 4; ++it) {
    int idx = t + it * 256;
    int row = idx >> 4;              // l-offset 0..63
    int c8  = (idx & 15) * 8;        // d 0..120
    short8 v = *(const short8*)&qkv_b[(size_t)(l0 + row) * TDIM + 2 * DIM + h * HD + c8];
#pragma unroll
    for (int j = 0; j < 8; ++j) *(short*)&T[c8 + j][row] = v[j];
  }
  __syncthreads();
#pragma unroll
  for (int it = 0; it < 4; ++it) {
    int idx = t + it * 256;
    int d = idx >> 3, c8 = (idx & 7) * 8;
    *(short8*)(Vt + ((size_t)h * HD + d) * L_SEQ + l0 + c8) = *(const short8*)&T[d][c8];
  }
}

// ---------------------------------------------------------------------------
// Flash attention, bf16 MFMA (unchanged from R2 — verified).
// ---------------------------------------------------------------------------
__global__ __launch_bounds__(256, 1)
void attn_mfma(const __hip_bfloat16* __restrict__ Qb,
               const __hip_bfloat16* __restrict__ Kb,
               const __hip_bfloat16* __restrict__ Vt,
               __hip_bfloat16* __restrict__ out) {
  const int q0 = blockIdx.x * 128;
  const int h  = blockIdx.y;
  const int t  = threadIdx.x;
  const int lane = t & 63, w = t >> 6;
  const int l15 = lane & 15, quad = lane >> 4;

  __shared__ __align__(16) __hip_bfloat16 Ks[64][136];
  __shared__ __align__(16) __hip_bfloat16 Vs[128][72];
  __shared__ __align__(16) __hip_bfloat16 Ps[128][72];

  short8 aq[2][4];
  const __hip_bfloat16* qbase = Qb + ((size_t)h * L_SEQ + q0 + w * 32) * HD;
#pragma unroll
  for (int mt = 0; mt < 2; ++mt)
#pragma unroll
    for (int ks = 0; ks < 4; ++ks)
      aq[mt][ks] = *(const short8*)(qbase + (size_t)(mt*16 + l15) * HD + ks*32 + quad*8);

  f32x4 o[2][8];
#pragma unroll
  for (int mt = 0; mt < 2; ++mt)
#pragma unroll
    for (int n2 = 0; n2 < 8; ++n2) o[mt][n2] = (f32x4){0.f, 0.f, 0.f, 0.f};
  float m_run[2][4], l_run[2][4];
#pragma unroll
  for (int mt = 0; mt < 2; ++mt)
#pragma unroll
    for (int r = 0; r < 4; ++r) { m_run[mt][r] = -1e30f; l_run[mt][r] = 0.f; }

  const __hip_bfloat16* kbase = Kb + (size_t)h * L_SEQ * HD;
  const __hip_bfloat16* vbase = Vt + (size_t)h * HD * L_SEQ;

  for (int kt = 0; kt < L_SEQ / 64; ++kt) {
    const int k0 = kt * 64;
#pragma unroll
    for (int it = 0; it < 4; ++it) {
      int idx = t + it * 256, row = idx >> 4, c8 = (idx & 15) * 8;
      *(short8*)&Ks[row][c8] = *(const short8*)(kbase + (size_t)(k0 + row) * HD + c8);
    }
#pragma unroll
    for (int it = 0; it < 4; ++it) {
      int idx = t + it * 256, d = idx >> 3, c8 = (idx & 7) * 8;
      *(short8*)&Vs[d][c8] = *(const short8*)(vbase + (size_t)d * L_SEQ + k0 + c8);
    }
    __syncthreads();

    f32x4 s[2][4];
#pragma unroll
    for (int mt = 0; mt < 2; ++mt)
#pragma unroll
      for (int nt = 0; nt < 4; ++nt) s[mt][nt] = (f32x4){0.f, 0.f, 0.f, 0.f};
#pragma unroll
    for (int ks = 0; ks < 4; ++ks) {
      short8 bk[4];
#pragma unroll
      for (int nt = 0; nt < 4; ++nt)
        bk[nt] = *(const short8*)&Ks[nt*16 + l15][ks*32 + quad*8];
#pragma unroll
      for (int mt = 0; mt < 2; ++mt)
#pragma unroll
        for (int nt = 0; nt < 4; ++nt)
          s[mt][nt] = __builtin_amdgcn_mfma_f32_16x16x32_bf16(aq[mt][ks], bk[nt], s[mt][nt], 0, 0, 0);
    }

#pragma unroll
    for (int mt = 0; mt < 2; ++mt) {
      float alpha[4];
#pragma unroll
      for (int r = 0; r < 4; ++r) {
        float rm = fmaxf(fmaxf(s[mt][0][r], s[mt][1][r]), fmaxf(s[mt][2][r], s[mt][3][r]));
#pragma unroll
        for (int off = 1; off < 16; off <<= 1) rm = fmaxf(rm, __shfl_xor(rm, off));
        float mnew = fmaxf(m_run[mt][r], rm);
        alpha[r] = __expf(m_run[mt][r] - mnew);
        m_run[mt][r] = mnew;
        float sum = 0.f;
#pragma unroll
        for (int nt = 0; nt < 4; ++nt) {
          float p = __expf(s[mt][nt][r] - mnew);
          s[mt][nt][r] = p;
          sum += p;
        }
#pragma unroll
        for (int off = 1; off < 16; off <<= 1) sum += __shfl_xor(sum, off);
        l_run[mt][r] = l_run[mt][r] * alpha[r] + sum;
      }
#pragma unroll
      for (int n2 = 0; n2 < 8; ++n2)
#pragma unroll
        for (int r = 0; r < 4; ++r) o[mt][n2][r] *= alpha[r];
#pragma unroll
      for (int nt = 0; nt < 4; ++nt)
#pragma unroll
        for (int r = 0; r < 4; ++r)
          Ps[w*32 + mt*16 + quad*4 + r][nt*16 + l15] = __float2bfloat16(s[mt][nt][r]);
    }
    __syncthreads();

#pragma unroll
    for (int ks2 = 0; ks2 < 2; ++ks2) {
      short8 ap[2];
#pragma unroll
      for (int mt = 0; mt < 2; ++mt)
        ap[mt] = *(const short8*)&Ps[w*32 + mt*16 + l15][ks2*32 + quad*8];
#pragma unroll
      for (int n2 = 0; n2 < 8; ++n2) {
        short8 bv = *(const short8*)&Vs[n2*16 + l15][ks2*32 + quad*8];
#pragma unroll
        for (int mt = 0; mt < 2; ++mt)
          o[mt][n2] = __builtin_amdgcn_mfma_f32_16x16x32_bf16(ap[mt], bv, o[mt][n2], 0, 0, 0);
      }
    }
    __syncthreads();
  }

#pragma unroll
  for (int mt = 0; mt < 2; ++mt)
#pragma unroll
    for (int r = 0; r < 4; ++r) {
      float inv = 1.f / l_run[mt][r];
      int q = q0 + w*32 + mt*16 + quad*4 + r;
#pragma unroll
      for (int n2 = 0; n2 < 8; ++n2)
        out[(size_t)q * DIM + h*HD + n2*16 + l15] = __float2bfloat16(o[mt][n2][r] * inv);
    }
}

// ---------------------------------------------------------------------------
extern "C" void kernel_launch(void* const* d_in, const int* in_sizes, int n_in,
                              void* d_out, int out_size, void* d_ws, size_t ws_size,
                              hipStream_t stream) {
  const float* x       = (const float*)d_in[0];
  const float* pe      = (const float*)d_in[1];
  const float* qkv_w   = (const float*)d_in[2];
  const float* q_scale = (const float*)d_in[3];
  const float* k_scale = (const float*)d_in[4];
  const float* proj_w  = (const float*)d_in[5];
  const float* proj_b  = (const float*)d_in[6];
  float* out = (float*)d_out;

  // Workspace (58.7 MB of the 67.1 MB footprint), with aliasing:
  //  region A [0, 25165824):        wb (qkv_w bf16)  -> Qb | Kb | Vt after QKV GEMM
  //  region B [25165824, 50331648): qkv_b bf16       -> pwb (proj_w bf16) after v_transpose
  //  region C [50331648, 58720256): xb (x bf16)      -> attn_out after QKV GEMM
  char* base = (char*)d_ws;
  __hip_bfloat16* wb       = (__hip_bfloat16*)base;
  __hip_bfloat16* qkv_b    = (__hip_bfloat16*)(base + 25165824);
  __hip_bfloat16* xb       = (__hip_bfloat16*)(base + 50331648);
  __hip_bfloat16* Qb       = (__hip_bfloat16*)base;
  __hip_bfloat16* Kb       = (__hip_bfloat16*)(base + 8388608);
  __hip_bfloat16* Vt       = (__hip_bfloat16*)(base + 16777216);
  __hip_bfloat16* pwb      = (__hip_bfloat16*)(base + 25165824);
  __hip_bfloat16* attn_out = (__hip_bfloat16*)(base + 50331648);

  cast_bf16<<<dim3(DIM * DIM / (256 * 8)), 256, 0, stream>>>(x, xb, DIM * DIM);
  cast_bf16<<<dim3(TDIM * DIM / (256 * 8)), 256, 0, stream>>>(qkv_w, wb, TDIM * DIM);

  gemm_mfma<0><<<dim3(TDIM / 128, L_SEQ / 128), 256, 0, stream>>>(
      xb, wb, nullptr, qkv_b, L_SEQ, TDIM, DIM);

  norm_rope<<<dim3(L_SEQ, 2 * NH), 128, 0, stream>>>(qkv_b, pe, q_scale, k_scale, Qb, Kb);
  v_transpose<<<dim3(L_SEQ / 64, NH), 256, 0, stream>>>(qkv_b, Vt);

  cast_bf16<<<dim3(DIM * DIM / (256 * 8)), 256, 0, stream>>>(proj_w, pwb, DIM * DIM);

  attn_mfma<<<dim3(L_SEQ / 128, NH), 256, 0, stream>>>(Qb, Kb, Vt, attn_out);

  gemm_mfma<1><<<dim3(DIM / 128, DIM / 128), 256, 0, stream>>>(
      attn_out, pwb, proj_b, out, L_SEQ, DIM, DIM);
}

// Round 4
// 354.165 us; speedup vs baseline: 5.3281x; 1.2683x over previous
//
#include <hip/hip_runtime.h>
#include <hip/hip_bf16.h>
#include <math.h>

#define L_SEQ 2048
#define DIM   2048
#define NH    16
#define HD    128
#define TDIM  6144

typedef __attribute__((ext_vector_type(8))) short short8;
typedef __attribute__((ext_vector_type(4))) float f32x4;

// async global->LDS, 16 B per lane. LDS dest = wave-uniform base + lane*16.
__device__ __forceinline__ void gl_lds16(const void* g, void* l) {
  __builtin_amdgcn_global_load_lds(
      (const __attribute__((address_space(1))) unsigned int*)g,
      (__attribute__((address_space(3))) unsigned int*)l, 16, 0, 0);
}

__device__ __forceinline__ short bf16bits(float x) {
  __hip_bfloat16 h = __float2bfloat16(x);
  return *(short*)&h;
}

// ---------------------------------------------------------------------------
// fp32 -> bf16 cast, 8 elements/thread.
// ---------------------------------------------------------------------------
__global__ __launch_bounds__(256)
void cast_bf16(const float* __restrict__ in, __hip_bfloat16* __restrict__ out, int n) {
  int i = (blockIdx.x * 256 + threadIdx.x) * 8;
  if (i >= n) return;
  float4 a = *(const float4*)(in + i);
  float4 b = *(const float4*)(in + i + 4);
  short8 o;
  o[0] = bf16bits(a.x); o[1] = bf16bits(a.y); o[2] = bf16bits(a.z); o[3] = bf16bits(a.w);
  o[4] = bf16bits(b.x); o[5] = bf16bits(b.y); o[6] = bf16bits(b.z); o[7] = bf16bits(b.w);
  *(short8*)(out + i) = o;
}

// ---------------------------------------------------------------------------
// bf16 MFMA GEMM (m97 structure): C[M][N] = A[M][K] * B[N][K]^T.
// 128x128 tile, BK=32, 4 waves, 4x4 16x16x32 MFMA tiles per wave,
// global_load_lds width-16 staging. OUT_MODE 0: bf16 C. 1: fp32 C + bias.
// (unchanged from R3 — verified)
// ---------------------------------------------------------------------------
template<int OUT_MODE>
__global__ __launch_bounds__(256)
void gemm_mfma(const __hip_bfloat16* __restrict__ A, const __hip_bfloat16* __restrict__ B,
               const float* __restrict__ bias, void* __restrict__ Cout,
               int M, int N, int K) {
  const int n0 = blockIdx.x * 128, m0 = blockIdx.y * 128;
  const int t = threadIdx.x, lane = t & 63, w = t >> 6;
  const int l15 = lane & 15, quad = lane >> 4;
  const int wm = (w & 1) * 64, wn = (w >> 1) * 64;

  __shared__ __align__(16) __hip_bfloat16 As[128 * 32];
  __shared__ __align__(16) __hip_bfloat16 Bs[128 * 32];

  f32x4 acc[4][4];
#pragma unroll
  for (int mt = 0; mt < 4; ++mt)
#pragma unroll
    for (int nt = 0; nt < 4; ++nt) acc[mt][nt] = (f32x4){0.f, 0.f, 0.f, 0.f};

  const int arow  = lane >> 2;
  const int acol8 = (lane & 3) * 8;
  const __hip_bfloat16* Ab = A + (size_t)(m0 + w * 16 + arow) * K + acol8;
  const __hip_bfloat16* Bb = B + (size_t)(n0 + w * 16 + arow) * K + acol8;
  __hip_bfloat16* As_base = As + (size_t)(w * 16) * 32;
  __hip_bfloat16* Bs_base = Bs + (size_t)(w * 16) * 32;

  for (int kb = 0; kb < K; kb += 32) {
    gl_lds16(Ab + kb,                As_base);
    gl_lds16(Ab + kb + (size_t)64*K, As_base + 64 * 32);
    gl_lds16(Bb + kb,                Bs_base);
    gl_lds16(Bb + kb + (size_t)64*K, Bs_base + 64 * 32);
    __syncthreads();

    short8 am[4], bn[4];
#pragma unroll
    for (int mt = 0; mt < 4; ++mt)
      am[mt] = *(const short8*)&As[(size_t)(wm + mt*16 + l15) * 32 + quad * 8];
#pragma unroll
    for (int nt = 0; nt < 4; ++nt)
      bn[nt] = *(const short8*)&Bs[(size_t)(wn + nt*16 + l15) * 32 + quad * 8];
#pragma unroll
    for (int mt = 0; mt < 4; ++mt)
#pragma unroll
      for (int nt = 0; nt < 4; ++nt)
        acc[mt][nt] = __builtin_amdgcn_mfma_f32_16x16x32_bf16(am[mt], bn[nt], acc[mt][nt], 0, 0, 0);
    __syncthreads();
  }

#pragma unroll
  for (int mt = 0; mt < 4; ++mt) {
#pragma unroll
    for (int nt = 0; nt < 4; ++nt) {
      int col = n0 + wn + nt * 16 + l15;
#pragma unroll
      for (int r = 0; r < 4; ++r) {
        int row = m0 + wm + mt * 16 + quad * 4 + r;
        if (OUT_MODE == 0) {
          ((__hip_bfloat16*)Cout)[(size_t)row * N + col] = __float2bfloat16(acc[mt][nt][r]);
        } else {
          ((float*)Cout)[(size_t)row * N + col] = acc[mt][nt][r] + bias[col];
        }
      }
    }
  }
}

// ---------------------------------------------------------------------------
// RMSNorm + RoPE on q,k (unchanged from R3 — verified).
// ---------------------------------------------------------------------------
__global__ __launch_bounds__(128)
void norm_rope(const __hip_bfloat16* __restrict__ qkv_b, const float* __restrict__ pe,
               const float* __restrict__ q_scale, const float* __restrict__ k_scale,
               __hip_bfloat16* __restrict__ Qb, __hip_bfloat16* __restrict__ Kb) {
  const int l  = blockIdx.x;
  const int hh = blockIdx.y;
  const int qk_sel = hh >> 4;
  const int h  = hh & 15;
  const int d  = threadIdx.x;
  const __hip_bfloat16* row = qkv_b + (size_t)l * TDIM + qk_sel * DIM + h * HD;
  const float* scale = qk_sel ? k_scale : q_scale;

  float v  = __bfloat162float(row[d]);
  float sq = v * v;
#pragma unroll
  for (int o = 32; o > 0; o >>= 1) sq += __shfl_xor(sq, o);
  __shared__ float wsum[2];
  if ((d & 63) == 0) wsum[d >> 6] = sq;
  __syncthreads();
  float rrms = rsqrtf((wsum[0] + wsum[1]) * (1.f / 128.f) + 1e-6f);
  __shared__ float nb[128];
  nb[d] = v * rrms * scale[d];
  __syncthreads();
  int i = d >> 1, c = d & 1;
  const float* p = pe + ((size_t)(l * 64 + i) * 2 + c) * 2;
  float res = p[0] * nb[2*i] + p[1] * nb[2*i + 1];
  size_t o_idx = ((size_t)h * L_SEQ + l) * HD + d;
  if (qk_sel == 0) Qb[o_idx] = __float2bfloat16(res * 0.08838834764831845f);
  else             Kb[o_idx] = __float2bfloat16(res);
}

// ---------------------------------------------------------------------------
// Transpose V -> Vt[h][d][l] bf16 (unchanged from R3 — verified).
// ---------------------------------------------------------------------------
__global__ __launch_bounds__(256)
void v_transpose(const __hip_bfloat16* __restrict__ qkv_b, __hip_bfloat16* __restrict__ Vt) {
  const int l0 = blockIdx.x * 64;
  const int h  = blockIdx.y;
  const int t  = threadIdx.x;
  __shared__ __align__(16) __hip_bfloat16 T[128][72];
#pragma unroll
  for (int it = 0; it < 4; ++it) {
    int idx = t + it * 256;
    int row = idx >> 4;
    int c8  = (idx & 15) * 8;
    short8 v = *(const short8*)&qkv_b[(size_t)(l0 + row) * TDIM + 2 * DIM + h * HD + c8];
#pragma unroll
    for (int j = 0; j < 8; ++j) *(short*)&T[c8 + j][row] = v[j];
  }
  __syncthreads();
#pragma unroll
  for (int it = 0; it < 4; ++it) {
    int idx = t + it * 256;
    int d = idx >> 3, c8 = (idx & 7) * 8;
    *(short8*)(Vt + ((size_t)h * HD + d) * L_SEQ + l0 + c8) = *(const short8*)&T[d][c8];
  }
}

// ---------------------------------------------------------------------------
// Flash attention v2: BQ=64 (16 q-rows/wave), BK=64, grid 512 -> 2 blocks/CU.
// K/Vt staged via global_load_lds (16B) into XOR-swizzled unpadded LDS
// (chunk' = chunk ^ (row&7)) -> conflict-free ds_read_b128 fragments.
// Double-buffered: tile kt+1 prefetch issued before kt's mid-barrier.
// ---------------------------------------------------------------------------
__global__ __launch_bounds__(256, 2)
void attn_mfma(const __hip_bfloat16* __restrict__ Qb,
               const __hip_bfloat16* __restrict__ Kb,
               const __hip_bfloat16* __restrict__ Vt,
               __hip_bfloat16* __restrict__ out) {
  const int q0 = blockIdx.x * 64;
  const int h  = blockIdx.y;
  const int t  = threadIdx.x;
  const int lane = t & 63, w = t >> 6;
  const int l15 = lane & 15, quad = lane >> 4;
  const int sw = l15 & 7;                    // read-side XOR swizzle key

  __shared__ __align__(16) __hip_bfloat16 Ks[2][64 * 128];   // [buf][row][chunk^ (row&7)]
  __shared__ __align__(16) __hip_bfloat16 Vs[2][128 * 64];   // [buf][d][chunk ^ (d&7)]
  __shared__ __align__(16) __hip_bfloat16 Ps[64][72];

  const __hip_bfloat16* kbase = Kb + (size_t)h * L_SEQ * HD;
  const __hip_bfloat16* vbase = Vt + (size_t)h * HD * L_SEQ;

  // Q fragments: rows w*16 + l15, k = ks*32 + quad*8 (Q pre-scaled by rsqrt(HD))
  short8 aq[4];
  {
    const __hip_bfloat16* qbase = Qb + ((size_t)h * L_SEQ + q0 + w * 16 + l15) * HD;
#pragma unroll
    for (int ks = 0; ks < 4; ++ks)
      aq[ks] = *(const short8*)(qbase + ks * 32 + quad * 8);
  }

  f32x4 o[8];
#pragma unroll
  for (int n2 = 0; n2 < 8; ++n2) o[n2] = (f32x4){0.f, 0.f, 0.f, 0.f};
  float m_run[4], l_run[4];
#pragma unroll
  for (int r = 0; r < 4; ++r) { m_run[r] = -1e30f; l_run[r] = 0.f; }

  // ---- staging (XOR-swizzled, async) ----
  // K: 64 rows x 16 chunks(16B). Per wave 4 ops x 4 rows.
  // V: 128 rows x 8 chunks(16B). Per wave 4 ops x 8 rows.
#define STAGE(buf, k0)                                                          \
  {                                                                             \
    _Pragma("unroll")                                                           \
    for (int i = 0; i < 4; ++i) {                                               \
      int krow = w * 16 + i * 4 + (lane >> 4);                                  \
      int kch  = (lane & 15) ^ (krow & 7);                                      \
      gl_lds16(kbase + (size_t)((k0) + krow) * HD + kch * 8,                    \
               &Ks[buf][(w * 16 + i * 4) * 128]);                               \
    }                                                                           \
    _Pragma("unroll")                                                           \
    for (int i = 0; i < 4; ++i) {                                               \
      int vrow = w * 32 + i * 8 + (lane >> 3);                                  \
      int vch  = (lane & 7) ^ (vrow & 7);                                       \
      gl_lds16(vbase + (size_t)vrow * L_SEQ + (k0) + vch * 8,                   \
               &Vs[buf][(w * 32 + i * 8) * 64]);                                \
    }                                                                           \
  }

  STAGE(0, 0);
  __syncthreads();

  for (int kt = 0; kt < L_SEQ / 64; ++kt) {
    const int cur = kt & 1;
    if (kt + 1 < L_SEQ / 64) STAGE(cur ^ 1, (kt + 1) * 64);

    // ---- S = Q K^T : 16 MFMA ----
    f32x4 s[4];
#pragma unroll
    for (int nt = 0; nt < 4; ++nt) s[nt] = (f32x4){0.f, 0.f, 0.f, 0.f};
#pragma unroll
    for (int ks = 0; ks < 4; ++ks) {
      short8 bk[4];
#pragma unroll
      for (int nt = 0; nt < 4; ++nt)
        bk[nt] = *(const short8*)&Ks[cur][(nt * 16 + l15) * 128 + ((ks * 4 + quad) ^ sw) * 8];
#pragma unroll
      for (int nt = 0; nt < 4; ++nt)
        s[nt] = __builtin_amdgcn_mfma_f32_16x16x32_bf16(aq[ks], bk[nt], s[nt], 0, 0, 0);
    }

    // ---- online softmax (rows: w*16 + quad*4 + r) ----
    float alpha[4];
#pragma unroll
    for (int r = 0; r < 4; ++r) {
      float rm = fmaxf(fmaxf(s[0][r], s[1][r]), fmaxf(s[2][r], s[3][r]));
#pragma unroll
      for (int off = 1; off < 16; off <<= 1) rm = fmaxf(rm, __shfl_xor(rm, off));
      float mnew = fmaxf(m_run[r], rm);
      alpha[r] = __expf(m_run[r] - mnew);
      m_run[r] = mnew;
      float sum = 0.f;
#pragma unroll
      for (int nt = 0; nt < 4; ++nt) {
        float p = __expf(s[nt][r] - mnew);
        s[nt][r] = p;
        sum += p;
      }
#pragma unroll
      for (int off = 1; off < 16; off <<= 1) sum += __shfl_xor(sum, off);
      l_run[r] = l_run[r] * alpha[r] + sum;
    }
#pragma unroll
    for (int n2 = 0; n2 < 8; ++n2)
#pragma unroll
      for (int r = 0; r < 4; ++r) o[n2][r] *= alpha[r];
#pragma unroll
    for (int nt = 0; nt < 4; ++nt)
#pragma unroll
      for (int r = 0; r < 4; ++r)
        Ps[w * 16 + quad * 4 + r][nt * 16 + l15] = __float2bfloat16(s[nt][r]);
    __syncthreads();   // Ps visible; prefetch vmcnt drained here too

    // ---- O += P Vt^T : 16 MFMA ----
#pragma unroll
    for (int ks2 = 0; ks2 < 2; ++ks2) {
      short8 ap = *(const short8*)&Ps[w * 16 + l15][ks2 * 32 + quad * 8];
#pragma unroll
      for (int n2 = 0; n2 < 8; ++n2) {
        short8 bv = *(const short8*)&Vs[cur][(n2 * 16 + l15) * 64 + ((ks2 * 4 + quad) ^ sw) * 8];
        o[n2] = __builtin_amdgcn_mfma_f32_16x16x32_bf16(ap, bv, o[n2], 0, 0, 0);
      }
    }
    __syncthreads();   // everyone done with Ks/Vs[cur] and Ps
  }

  // epilogue: out[q][h*128 + d] bf16
#pragma unroll
  for (int r = 0; r < 4; ++r) {
    float inv = 1.f / l_run[r];
    int q = q0 + w * 16 + quad * 4 + r;
#pragma unroll
    for (int n2 = 0; n2 < 8; ++n2)
      out[(size_t)q * DIM + h * HD + n2 * 16 + l15] = __float2bfloat16(o[n2][r] * inv);
  }
#undef STAGE
}

// ---------------------------------------------------------------------------
extern "C" void kernel_launch(void* const* d_in, const int* in_sizes, int n_in,
                              void* d_out, int out_size, void* d_ws, size_t ws_size,
                              hipStream_t stream) {
  const float* x       = (const float*)d_in[0];
  const float* pe      = (const float*)d_in[1];
  const float* qkv_w   = (const float*)d_in[2];
  const float* q_scale = (const float*)d_in[3];
  const float* k_scale = (const float*)d_in[4];
  const float* proj_w  = (const float*)d_in[5];
  const float* proj_b  = (const float*)d_in[6];
  float* out = (float*)d_out;

  // Workspace aliasing (58.7 MB):
  //  region A [0, 25165824):        wb (qkv_w bf16)  -> Qb | Kb | Vt after QKV GEMM
  //  region B [25165824, 50331648): qkv_b bf16       -> pwb (proj_w bf16) after v_transpose
  //  region C [50331648, 58720256): xb (x bf16)      -> attn_out after QKV GEMM
  char* base = (char*)d_ws;
  __hip_bfloat16* wb       = (__hip_bfloat16*)base;
  __hip_bfloat16* qkv_b    = (__hip_bfloat16*)(base + 25165824);
  __hip_bfloat16* xb       = (__hip_bfloat16*)(base + 50331648);
  __hip_bfloat16* Qb       = (__hip_bfloat16*)base;
  __hip_bfloat16* Kb       = (__hip_bfloat16*)(base + 8388608);
  __hip_bfloat16* Vt       = (__hip_bfloat16*)(base + 16777216);
  __hip_bfloat16* pwb      = (__hip_bfloat16*)(base + 25165824);
  __hip_bfloat16* attn_out = (__hip_bfloat16*)(base + 50331648);

  cast_bf16<<<dim3(DIM * DIM / (256 * 8)), 256, 0, stream>>>(x, xb, DIM * DIM);
  cast_bf16<<<dim3(TDIM * DIM / (256 * 8)), 256, 0, stream>>>(qkv_w, wb, TDIM * DIM);

  gemm_mfma<0><<<dim3(TDIM / 128, L_SEQ / 128), 256, 0, stream>>>(
      xb, wb, nullptr, qkv_b, L_SEQ, TDIM, DIM);

  norm_rope<<<dim3(L_SEQ, 2 * NH), 128, 0, stream>>>(qkv_b, pe, q_scale, k_scale, Qb, Kb);
  v_transpose<<<dim3(L_SEQ / 64, NH), 256, 0, stream>>>(qkv_b, Vt);

  cast_bf16<<<dim3(DIM * DIM / (256 * 8)), 256, 0, stream>>>(proj_w, pwb, DIM * DIM);

  attn_mfma<<<dim3(L_SEQ / 64, NH), 256, 0, stream>>>(Qb, Kb, Vt, attn_out);

  gemm_mfma<1><<<dim3(DIM / 128, DIM / 128), 256, 0, stream>>>(
      attn_out, pwb, proj_b, out, L_SEQ, DIM, DIM);
}

// Round 5
// 341.863 us; speedup vs baseline: 5.5199x; 1.0360x over previous
//
#include <hip/hip_runtime.h>
#include <hip/hip_bf16.h>
#include <math.h>

#define L_SEQ 2048
#define DIM   2048
#define NH    16
#define HD    128
#define TDIM  6144

typedef __attribute__((ext_vector_type(8))) short short8;
typedef __attribute__((ext_vector_type(4))) float f32x4;
typedef __attribute__((ext_vector_type(4))) unsigned int u32x4;

// async global->LDS, 16 B per lane. LDS dest = wave-uniform base + lane*16.
__device__ __forceinline__ void gl_lds16(const void* g, void* l) {
  __builtin_amdgcn_global_load_lds(
      (const __attribute__((address_space(1))) unsigned int*)g,
      (__attribute__((address_space(3))) unsigned int*)l, 16, 0, 0);
}

__device__ __forceinline__ short bf16bits(float x) {
  __hip_bfloat16 h = __float2bfloat16(x);
  return *(short*)&h;
}

// pack two f32 -> u32 of two bf16 (lo = a, hi = b)
__device__ __forceinline__ unsigned int pack_bf16(float a, float b) {
  __hip_bfloat162 h = __float22bfloat162_rn(make_float2(a, b));
  return *(unsigned int*)&h;
}

// ---------------------------------------------------------------------------
// fp32 -> bf16 cast, 8 elements/thread.
// ---------------------------------------------------------------------------
__global__ __launch_bounds__(256)
void cast_bf16(const float* __restrict__ in, __hip_bfloat16* __restrict__ out, int n) {
  int i = (blockIdx.x * 256 + threadIdx.x) * 8;
  if (i >= n) return;
  float4 a = *(const float4*)(in + i);
  float4 b = *(const float4*)(in + i + 4);
  short8 o;
  o[0] = bf16bits(a.x); o[1] = bf16bits(a.y); o[2] = bf16bits(a.z); o[3] = bf16bits(a.w);
  o[4] = bf16bits(b.x); o[5] = bf16bits(b.y); o[6] = bf16bits(b.z); o[7] = bf16bits(b.w);
  *(short8*)(out + i) = o;
}

// ---------------------------------------------------------------------------
// bf16 MFMA GEMM (m97 structure) — unchanged from R3/R4, verified.
// ---------------------------------------------------------------------------
template<int OUT_MODE>
__global__ __launch_bounds__(256)
void gemm_mfma(const __hip_bfloat16* __restrict__ A, const __hip_bfloat16* __restrict__ B,
               const float* __restrict__ bias, void* __restrict__ Cout,
               int M, int N, int K) {
  const int n0 = blockIdx.x * 128, m0 = blockIdx.y * 128;
  const int t = threadIdx.x, lane = t & 63, w = t >> 6;
  const int l15 = lane & 15, quad = lane >> 4;
  const int wm = (w & 1) * 64, wn = (w >> 1) * 64;

  __shared__ __align__(16) __hip_bfloat16 As[128 * 32];
  __shared__ __align__(16) __hip_bfloat16 Bs[128 * 32];

  f32x4 acc[4][4];
#pragma unroll
  for (int mt = 0; mt < 4; ++mt)
#pragma unroll
    for (int nt = 0; nt < 4; ++nt) acc[mt][nt] = (f32x4){0.f, 0.f, 0.f, 0.f};

  const int arow  = lane >> 2;
  const int acol8 = (lane & 3) * 8;
  const __hip_bfloat16* Ab = A + (size_t)(m0 + w * 16 + arow) * K + acol8;
  const __hip_bfloat16* Bb = B + (size_t)(n0 + w * 16 + arow) * K + acol8;
  __hip_bfloat16* As_base = As + (size_t)(w * 16) * 32;
  __hip_bfloat16* Bs_base = Bs + (size_t)(w * 16) * 32;

  for (int kb = 0; kb < K; kb += 32) {
    gl_lds16(Ab + kb,                As_base);
    gl_lds16(Ab + kb + (size_t)64*K, As_base + 64 * 32);
    gl_lds16(Bb + kb,                Bs_base);
    gl_lds16(Bb + kb + (size_t)64*K, Bs_base + 64 * 32);
    __syncthreads();

    short8 am[4], bn[4];
#pragma unroll
    for (int mt = 0; mt < 4; ++mt)
      am[mt] = *(const short8*)&As[(size_t)(wm + mt*16 + l15) * 32 + quad * 8];
#pragma unroll
    for (int nt = 0; nt < 4; ++nt)
      bn[nt] = *(const short8*)&Bs[(size_t)(wn + nt*16 + l15) * 32 + quad * 8];
#pragma unroll
    for (int mt = 0; mt < 4; ++mt)
#pragma unroll
      for (int nt = 0; nt < 4; ++nt)
        acc[mt][nt] = __builtin_amdgcn_mfma_f32_16x16x32_bf16(am[mt], bn[nt], acc[mt][nt], 0, 0, 0);
    __syncthreads();
  }

#pragma unroll
  for (int mt = 0; mt < 4; ++mt) {
#pragma unroll
    for (int nt = 0; nt < 4; ++nt) {
      int col = n0 + wn + nt * 16 + l15;
#pragma unroll
      for (int r = 0; r < 4; ++r) {
        int row = m0 + wm + mt * 16 + quad * 4 + r;
        if (OUT_MODE == 0) {
          ((__hip_bfloat16*)Cout)[(size_t)row * N + col] = __float2bfloat16(acc[mt][nt][r]);
        } else {
          ((float*)Cout)[(size_t)row * N + col] = acc[mt][nt][r] + bias[col];
        }
      }
    }
  }
}

// ---------------------------------------------------------------------------
// RMSNorm + RoPE on q,k (unchanged — verified).
// ---------------------------------------------------------------------------
__global__ __launch_bounds__(128)
void norm_rope(const __hip_bfloat16* __restrict__ qkv_b, const float* __restrict__ pe,
               const float* __restrict__ q_scale, const float* __restrict__ k_scale,
               __hip_bfloat16* __restrict__ Qb, __hip_bfloat16* __restrict__ Kb) {
  const int l  = blockIdx.x;
  const int hh = blockIdx.y;
  const int qk_sel = hh >> 4;
  const int h  = hh & 15;
  const int d  = threadIdx.x;
  const __hip_bfloat16* row = qkv_b + (size_t)l * TDIM + qk_sel * DIM + h * HD;
  const float* scale = qk_sel ? k_scale : q_scale;

  float v  = __bfloat162float(row[d]);
  float sq = v * v;
#pragma unroll
  for (int o = 32; o > 0; o >>= 1) sq += __shfl_xor(sq, o);
  __shared__ float wsum[2];
  if ((d & 63) == 0) wsum[d >> 6] = sq;
  __syncthreads();
  float rrms = rsqrtf((wsum[0] + wsum[1]) * (1.f / 128.f) + 1e-6f);
  __shared__ float nb[128];
  nb[d] = v * rrms * scale[d];
  __syncthreads();
  int i = d >> 1, c = d & 1;
  const float* p = pe + ((size_t)(l * 64 + i) * 2 + c) * 2;
  float res = p[0] * nb[2*i] + p[1] * nb[2*i + 1];
  size_t o_idx = ((size_t)h * L_SEQ + l) * HD + d;
  if (qk_sel == 0) Qb[o_idx] = __float2bfloat16(res * 0.08838834764831845f);
  else             Kb[o_idx] = __float2bfloat16(res);
}

// ---------------------------------------------------------------------------
// Transpose V -> Vt[h][d][l] bf16 (unchanged — verified).
// ---------------------------------------------------------------------------
__global__ __launch_bounds__(256)
void v_transpose(const __hip_bfloat16* __restrict__ qkv_b, __hip_bfloat16* __restrict__ Vt) {
  const int l0 = blockIdx.x * 64;
  const int h  = blockIdx.y;
  const int t  = threadIdx.x;
  __shared__ __align__(16) __hip_bfloat16 T[128][72];
#pragma unroll
  for (int it = 0; it < 4; ++it) {
    int idx = t + it * 256;
    int row = idx >> 4;
    int c8  = (idx & 15) * 8;
    short8 v = *(const short8*)&qkv_b[(size_t)(l0 + row) * TDIM + 2 * DIM + h * HD + c8];
#pragma unroll
    for (int j = 0; j < 8; ++j) *(short*)&T[c8 + j][row] = v[j];
  }
  __syncthreads();
#pragma unroll
  for (int it = 0; it < 4; ++it) {
    int idx = t + it * 256;
    int d = idx >> 3, c8 = (idx & 7) * 8;
    *(short8*)(Vt + ((size_t)h * HD + d) * L_SEQ + l0 + c8) = *(const short8*)&T[d][c8];
  }
}

// ---------------------------------------------------------------------------
// Flash attention v3: S^T formulation, one barrier per ktile.
//  - S^T = K·Q^T (operand-swapped MFMA): lane owns q=lane&15, kv in regs.
//  - softmax: in-register 16-value max/sum + 2 cross-quad shfl_xor; 1 alpha
//    exp per lane.
//  - P (C-layout of S^T) -> PV A-layout in-register: 16 independent shfl
//    + 8 selects. No Ps LDS, no mid barrier.
//  - K/V double-buffered; prefetch overlaps whole tile (single barrier).
// ---------------------------------------------------------------------------
__global__ __launch_bounds__(256, 2)
void attn_mfma(const __hip_bfloat16* __restrict__ Qb,
               const __hip_bfloat16* __restrict__ Kb,
               const __hip_bfloat16* __restrict__ Vt,
               __hip_bfloat16* __restrict__ out) {
  const int q0 = blockIdx.x * 64;
  const int h  = blockIdx.y;
  const int t  = threadIdx.x;
  const int lane = t & 63, w = t >> 6;
  const int l15 = lane & 15, quad = lane >> 4;
  const int sw = l15 & 7;                    // read-side XOR swizzle key

  __shared__ __align__(16) __hip_bfloat16 Ks[2][64 * 128];   // [buf][row][chunk ^ (row&7)]
  __shared__ __align__(16) __hip_bfloat16 Vs[2][128 * 64];   // [buf][d][chunk ^ (d&7)]

  const __hip_bfloat16* kbase = Kb + (size_t)h * L_SEQ * HD;
  const __hip_bfloat16* vbase = Vt + (size_t)h * HD * L_SEQ;

  // Q fragments (B-operand): n-rows q = w*16 + l15, k = ks*32 + quad*8
  short8 aq[4];
  {
    const __hip_bfloat16* qbase = Qb + ((size_t)h * L_SEQ + q0 + w * 16 + l15) * HD;
#pragma unroll
    for (int ks = 0; ks < 4; ++ks)
      aq[ks] = *(const short8*)(qbase + ks * 32 + quad * 8);
  }

  f32x4 o[8];
#pragma unroll
  for (int n2 = 0; n2 < 8; ++n2) o[n2] = (f32x4){0.f, 0.f, 0.f, 0.f};
  float m_run = -1e30f, l_run = 0.f;   // per lane, q = w*16 + l15 (dup x4 quads)

#define STAGE(buf, k0)                                                          \
  {                                                                             \
    _Pragma("unroll")                                                           \
    for (int i = 0; i < 4; ++i) {                                               \
      int krow = w * 16 + i * 4 + (lane >> 4);                                  \
      int kch  = (lane & 15) ^ (krow & 7);                                      \
      gl_lds16(kbase + (size_t)((k0) + krow) * HD + kch * 8,                    \
               &Ks[buf][(w * 16 + i * 4) * 128]);                               \
    }                                                                           \
    _Pragma("unroll")                                                           \
    for (int i = 0; i < 4; ++i) {                                               \
      int vrow = w * 32 + i * 8 + (lane >> 3);                                  \
      int vch  = (lane & 7) ^ (vrow & 7);                                       \
      gl_lds16(vbase + (size_t)vrow * L_SEQ + (k0) + vch * 8,                   \
               &Vs[buf][(w * 32 + i * 8) * 64]);                                \
    }                                                                           \
  }

  STAGE(0, 0);
  __syncthreads();

  for (int kt = 0; kt < L_SEQ / 64; ++kt) {
    const int cur = kt & 1;
    if (kt + 1 < L_SEQ / 64) STAGE(cur ^ 1, (kt + 1) * 64);

    // ---- S^T = K Q^T : 16 MFMA. s[nt][r]: kv = nt*16+quad*4+r, q = l15 ----
    f32x4 s[4];
#pragma unroll
    for (int nt = 0; nt < 4; ++nt) s[nt] = (f32x4){0.f, 0.f, 0.f, 0.f};
#pragma unroll
    for (int ks = 0; ks < 4; ++ks) {
      short8 bk[4];
#pragma unroll
      for (int nt = 0; nt < 4; ++nt)
        bk[nt] = *(const short8*)&Ks[cur][(nt * 16 + l15) * 128 + ((ks * 4 + quad) ^ sw) * 8];
#pragma unroll
      for (int nt = 0; nt < 4; ++nt)
        s[nt] = __builtin_amdgcn_mfma_f32_16x16x32_bf16(bk[nt], aq[ks], s[nt], 0, 0, 0);
    }

    // ---- online softmax, in-register over 16 kv values + cross-quad ----
    float mx0 = fmaxf(fmaxf(s[0][0], s[0][1]), fmaxf(s[0][2], s[0][3]));
    float mx1 = fmaxf(fmaxf(s[1][0], s[1][1]), fmaxf(s[1][2], s[1][3]));
    float mx2 = fmaxf(fmaxf(s[2][0], s[2][1]), fmaxf(s[2][2], s[2][3]));
    float mx3 = fmaxf(fmaxf(s[3][0], s[3][1]), fmaxf(s[3][2], s[3][3]));
    float rm = fmaxf(fmaxf(mx0, mx1), fmaxf(mx2, mx3));
    rm = fmaxf(rm, __shfl_xor(rm, 16));
    rm = fmaxf(rm, __shfl_xor(rm, 32));
    float mnew = fmaxf(m_run, rm);
    float alpha = __expf(m_run - mnew);
    m_run = mnew;

    float sum = 0.f;
#pragma unroll
    for (int nt = 0; nt < 4; ++nt)
#pragma unroll
      for (int r = 0; r < 4; ++r) {
        float p = __expf(s[nt][r] - mnew);
        s[nt][r] = p;
        sum += p;
      }
    sum += __shfl_xor(sum, 16);
    sum += __shfl_xor(sum, 32);
    l_run = l_run * alpha + sum;

    // O *= alpha (alpha for q=quad*4+r lives at lane quad*4+r)
    float alpha_r[4];
#pragma unroll
    for (int r = 0; r < 4; ++r) alpha_r[r] = __shfl(alpha, quad * 4 + r);
#pragma unroll
    for (int n2 = 0; n2 < 8; ++n2)
#pragma unroll
      for (int r = 0; r < 4; ++r) o[n2][r] *= alpha_r[r];

    // ---- P: C-layout -> A-layout in-register (16 shfl + 8 sel) ----
    // source pack: pk[nt][rp] = bf16x2(s[nt][2rp], s[nt][2rp+1]), kv=nt*16+quad*4+2rp
    unsigned int pk[4][2];
#pragma unroll
    for (int nt = 0; nt < 4; ++nt) {
      pk[nt][0] = pack_bf16(s[nt][0], s[nt][1]);
      pk[nt][1] = pack_bf16(s[nt][2], s[nt][3]);
    }
    short8 ap[2];
#pragma unroll
    for (int ks2 = 0; ks2 < 2; ++ks2) {
      u32x4 a32;
#pragma unroll
      for (int jp = 0; jp < 4; ++jp) {
        // target kv_lo = ks2*32 + quad*8 + 2*jp  (q = l15)
        int quad_src = (quad & 1) * 2 + (jp >> 1);
        int src = (quad_src << 4) | l15;
        int rp = jp & 1;
        unsigned int v0 = __shfl((int)pk[2 * ks2 + 0][rp], src);
        unsigned int v1 = __shfl((int)pk[2 * ks2 + 1][rp], src);
        a32[jp] = (quad >> 1) ? v1 : v0;
      }
      ap[ks2] = *(short8*)&a32;
    }

    // ---- O += P Vt^T : 16 MFMA ----
#pragma unroll
    for (int ks2 = 0; ks2 < 2; ++ks2)
#pragma unroll
      for (int n2 = 0; n2 < 8; ++n2) {
        short8 bv = *(const short8*)&Vs[cur][(n2 * 16 + l15) * 64 + ((ks2 * 4 + quad) ^ sw) * 8];
        o[n2] = __builtin_amdgcn_mfma_f32_16x16x32_bf16(ap[ks2], bv, o[n2], 0, 0, 0);
      }

    __syncthreads();   // all waves done with [cur]; prefetch [cur^1] drained
  }

  // epilogue: o[n2][r]: q = quad*4+r, d = n2*16+l15 ; l for q at lane quad*4+r
  float linv[4];
#pragma unroll
  for (int r = 0; r < 4; ++r) linv[r] = 1.f / __shfl(l_run, quad * 4 + r);
#pragma unroll
  for (int r = 0; r < 4; ++r) {
    int q = q0 + w * 16 + quad * 4 + r;
#pragma unroll
    for (int n2 = 0; n2 < 8; ++n2)
      out[(size_t)q * DIM + h * HD + n2 * 16 + l15] = __float2bfloat16(o[n2][r] * linv[r]);
  }
#undef STAGE
}

// ---------------------------------------------------------------------------
extern "C" void kernel_launch(void* const* d_in, const int* in_sizes, int n_in,
                              void* d_out, int out_size, void* d_ws, size_t ws_size,
                              hipStream_t stream) {
  const float* x       = (const float*)d_in[0];
  const float* pe      = (const float*)d_in[1];
  const float* qkv_w   = (const float*)d_in[2];
  const float* q_scale = (const float*)d_in[3];
  const float* k_scale = (const float*)d_in[4];
  const float* proj_w  = (const float*)d_in[5];
  const float* proj_b  = (const float*)d_in[6];
  float* out = (float*)d_out;

  // Workspace aliasing (58.7 MB):
  //  region A [0, 25165824):        wb (qkv_w bf16)  -> Qb | Kb | Vt after QKV GEMM
  //  region B [25165824, 50331648): qkv_b bf16       -> pwb (proj_w bf16) after v_transpose
  //  region C [50331648, 58720256): xb (x bf16)      -> attn_out after QKV GEMM
  char* base = (char*)d_ws;
  __hip_bfloat16* wb       = (__hip_bfloat16*)base;
  __hip_bfloat16* qkv_b    = (__hip_bfloat16*)(base + 25165824);
  __hip_bfloat16* xb       = (__hip_bfloat16*)(base + 50331648);
  __hip_bfloat16* Qb       = (__hip_bfloat16*)base;
  __hip_bfloat16* Kb       = (__hip_bfloat16*)(base + 8388608);
  __hip_bfloat16* Vt       = (__hip_bfloat16*)(base + 16777216);
  __hip_bfloat16* pwb      = (__hip_bfloat16*)(base + 25165824);
  __hip_bfloat16* attn_out = (__hip_bfloat16*)(base + 50331648);

  cast_bf16<<<dim3(DIM * DIM / (256 * 8)), 256, 0, stream>>>(x, xb, DIM * DIM);
  cast_bf16<<<dim3(TDIM * DIM / (256 * 8)), 256, 0, stream>>>(qkv_w, wb, TDIM * DIM);

  gemm_mfma<0><<<dim3(TDIM / 128, L_SEQ / 128), 256, 0, stream>>>(
      xb, wb, nullptr, qkv_b, L_SEQ, TDIM, DIM);

  norm_rope<<<dim3(L_SEQ, 2 * NH), 128, 0, stream>>>(qkv_b, pe, q_scale, k_scale, Qb, Kb);
  v_transpose<<<dim3(L_SEQ / 64, NH), 256, 0, stream>>>(qkv_b, Vt);

  cast_bf16<<<dim3(DIM * DIM / (256 * 8)), 256, 0, stream>>>(proj_w, pwb, DIM * DIM);

  attn_mfma<<<dim3(L_SEQ / 64, NH), 256, 0, stream>>>(Qb, Kb, Vt, attn_out);

  gemm_mfma<1><<<dim3(DIM / 128, DIM / 128), 256, 0, stream>>>(
      attn_out, pwb, proj_b, out, L_SEQ, DIM, DIM);
}